// Round 2
// baseline (57.046 us; speedup 1.0000x reference)
//
#include <hip/hip_runtime.h>

typedef _Float16 f16;
typedef _Float16 f16x2 __attribute__((ext_vector_type(2)));
typedef __fp16   h16x2 __attribute__((ext_vector_type(2)));   // cvt_pkrtz native return
typedef _Float16 f16x4 __attribute__((ext_vector_type(4)));
typedef float    f32x4 __attribute__((ext_vector_type(4)));
typedef unsigned int u32;
typedef unsigned int u32x2v __attribute__((ext_vector_type(2)));

#define NB 4
#define NS 2048
#define NH 16
#define NDK 8
#define NE 128
// log2(e)/sqrt(8): exp(dot/sqrt(8)) == exp2(dot * CSCALE)
#define CSCALE 0.51006972f

__device__ __forceinline__ float fexp2(float v){
#if __has_builtin(__builtin_amdgcn_exp2f)
  return __builtin_amdgcn_exp2f(v);
#else
  return exp2f(v);
#endif
}

__device__ __forceinline__ f16x2 pkrtz(float a, float b){
  return __builtin_bit_cast(f16x2, __builtin_amdgcn_cvt_pkrtz(a, b));
}

__device__ __forceinline__ float fdot2a(f16x2 a, f16x2 b, float c){
#if __has_builtin(__builtin_amdgcn_fdot2)
  return __builtin_amdgcn_fdot2(a, b, c, false);
#else
  return c + (float)a[0]*(float)b[0] + (float)a[1]*(float)b[1];
#endif
}

// ---------------------------------------------------------------------------
// Attention kernel: one block = one (b,h) pair x 256 query rows.
// q=k=v = cos(x+theta) computed in-staging (f16).
// LDS: Kl = rows [2048][8] f16 (32KB), Vl = V^T [8][2048] f16 XOR-swizzled (32KB).
// Per wave: 64 q-rows (4 x 16). Loop over 128 key-tiles of 16:
//   S^T tile = mfma16x16x16f16(A=K-rows, B=Q-rows)   (dk=8 zero-padded via B)
//   P = exp2(S^T * c)  -> cvt_pkrtz -> directly the B-operand of
//   out^T += mfma16x16x16f16(A=V^T (row8==ones), B=P^T)
// Row 8 of out^T accumulator = softmax denominator (ones trick).
// ---------------------------------------------------------------------------
__global__ __launch_bounds__(256, 2) void qattn(const float* __restrict__ x,
                                                const float* __restrict__ theta,
                                                float* __restrict__ out){
  __shared__ __align__(16) uint2 Kl[NS*2];   // [s][2] : 16B per row
  __shared__ __align__(16) uint2 Vl[8*512];  // [d][512 8B-granules, swizzled]

  const int bid = blockIdx.x;
  const int bh  = bid >> 3;       // 0..63
  const int qc  = bid & 7;        // q-chunk of 256 rows
  const int b   = bh >> 4;
  const int h   = bh & 15;
  const int tid = threadIdx.x;

  const float4 th0 = *(const float4*)(theta);
  const float4 th1 = *(const float4*)(theta + 4);

  // ---- stage: compute cos(x+theta) for all 2048 rows of this (b,h) ----
  const float* xb = x + ((size_t)b*NS*NH + h)*NDK;
  unsigned short* Vs = (unsigned short*)Vl;
  #pragma unroll
  for(int i=0;i<8;++i){
    int s = tid + 256*i;
    const float4* xp = (const float4*)(xb + (size_t)s*(NH*NDK));
    float4 x0 = xp[0], x1 = xp[1];
    union { f16 hh[8]; uint4 u; } pk;
    pk.hh[0] = (f16)__cosf(x0.x + th0.x);
    pk.hh[1] = (f16)__cosf(x0.y + th0.y);
    pk.hh[2] = (f16)__cosf(x0.z + th0.z);
    pk.hh[3] = (f16)__cosf(x0.w + th0.w);
    pk.hh[4] = (f16)__cosf(x1.x + th1.x);
    pk.hh[5] = (f16)__cosf(x1.y + th1.y);
    pk.hh[6] = (f16)__cosf(x1.z + th1.z);
    pk.hh[7] = (f16)__cosf(x1.w + th1.w);
    ((uint4*)Kl)[s] = pk.u;
    int sb = s >> 2, sl = s & 3;
    #pragma unroll
    for(int d=0;d<8;++d)
      Vs[(d<<11) + (((sb ^ d)<<2) | sl)] =
          __builtin_bit_cast(unsigned short, pk.hh[d]);
  }
  __syncthreads();

  const int lane = tid & 63;
  const int w    = tid >> 6;
  const int c    = lane & 15;     // column role (q for QK-B / d for V-A)
  const int grp  = lane >> 4;     // 0..3
  const int g1   = grp & 1;
  const bool lo32  = (lane < 32);
  const bool creal = (c < 8);
  const int dvx  = c & 7;
  const int qbase = qc*256 + w*64;

  // hoisted Q fragments (B operand of swapped QK); zero lanes>=32 pads dk 8->16
  f16x4 qf[4];
  #pragma unroll
  for(int sub=0; sub<4; ++sub){
    uint2 qv = Kl[(qbase + sub*16 + c)*2 + g1];
    if(!lo32){ qv.x = 0u; qv.y = 0u; }
    qf[sub] = __builtin_bit_cast(f16x4, qv);
  }

  const f32x4 z4 = {0.f,0.f,0.f,0.f};
  f32x4 acc[4] = {z4,z4,z4,z4};
  uint2 ones2; ones2.x = 0x3C003C00u; ones2.y = 0x3C003C00u;  // f16 1.0 x4

  const uint2* kptr = &Kl[c*2 + g1];
  for(int kt=0; kt<128; ++kt){
    uint2 ka = kptr[kt*32];                                 // K row kt*16+c
    uint2 va = Vl[(dvx<<9) | (((kt<<2) + grp) ^ dvx)];      // V^T row c
    if(!creal) va = ones2;                                  // rows 8..15 = 1.0
    f16x4 kf = __builtin_bit_cast(f16x4, ka);
    f16x4 vf = __builtin_bit_cast(f16x4, va);
    #pragma unroll
    for(int sub=0; sub<4; ++sub){
      f32x4 st = __builtin_amdgcn_mfma_f32_16x16x16f16(kf, qf[sub], z4, 0, 0, 0);
      float p0 = fexp2(st[0]*CSCALE);
      float p1 = fexp2(st[1]*CSCALE);
      float p2 = fexp2(st[2]*CSCALE);
      float p3 = fexp2(st[3]*CSCALE);
      f16x2 plo = pkrtz(p0, p1);
      f16x2 phi = pkrtz(p2, p3);
      u32x2v pu = { __builtin_bit_cast(u32, plo), __builtin_bit_cast(u32, phi) };
      f16x4 pf = __builtin_bit_cast(f16x4, pu);
      acc[sub] = __builtin_amdgcn_mfma_f32_16x16x16f16(vf, pf, acc[sub], 0, 0, 0);
    }
  }

  // epilogue: acc row 8 (lane 32+c, reg0) = denominator for column q=c
  #pragma unroll
  for(int sub=0; sub<4; ++sub){
    float den = __shfl(acc[sub][0], 32 + c, 64);
    if(lo32){
      float inv = 1.0f / den;
      int q = qbase + sub*16 + c;
      float4 o;
      o.x = acc[sub][0]*inv;
      o.y = acc[sub][1]*inv;
      o.z = acc[sub][2]*inv;
      o.w = acc[sub][3]*inv;
      // attn_out[b][q][h][d], d = 4*grp + r  (written into d_out as scratch)
      *(float4*)(out + ((size_t)(b*NS + q)*NH + h)*NDK + grp*4) = o;
    }
  }
}

// ---------------------------------------------------------------------------
// Combine: out = attn @ W^T + bias, in-place on d_out.
// Block = 32 rows. A rows staged to LDS (f16 pairs) BEFORE overwrite -> safe
// in-place. W transposed to half2 pairs in LDS (padded stride 132 for
// conflict-free b128 reads). Inner loop uses v_dot2_f32_f16.
// ---------------------------------------------------------------------------
__global__ __launch_bounds__(256) void qcomb(const float* __restrict__ W,
                                             const float* __restrict__ bias,
                                             float* __restrict__ io){
  __shared__ __align__(16) u32 Wt[64*132];   // Wt[e2*132 + j] = {W[j][2e2],W[j][2e2+1]}
  __shared__ __align__(16) u32 A2[32*65];    // A2[r*65 + e2]  = {A[r][2e2],A[r][2e2+1]}
  const int tid = threadIdx.x;
  const size_t row0 = (size_t)blockIdx.x * 32;

  #pragma unroll
  for(int i=0;i<32;++i){
    int g = tid + 256*i;          // 0..8191
    int j = g >> 6, e2 = g & 63;
    const float* wp = W + (size_t)j*NE + 2*e2;
    f16x2 wv = pkrtz(wp[0], wp[1]);
    Wt[e2*132 + j] = __builtin_bit_cast(u32, wv);
  }
  #pragma unroll
  for(int i=0;i<8;++i){
    int g = tid + 256*i;          // 0..2047
    int r = g >> 6, e2 = g & 63;
    const float* ap = io + (row0 + r)*NE + 2*e2;
    f16x2 av = pkrtz(ap[0], ap[1]);
    A2[r*65 + e2] = __builtin_bit_cast(u32, av);
  }
  __syncthreads();

  const int tr = tid >> 4, tc = tid & 15;
  float acc0[8] = {0,0,0,0,0,0,0,0};
  float acc1[8] = {0,0,0,0,0,0,0,0};
  for(int e2=0; e2<64; ++e2){
    f16x2 a0 = __builtin_bit_cast(f16x2, A2[tr*65 + e2]);
    f16x2 a1 = __builtin_bit_cast(f16x2, A2[(tr+16)*65 + e2]);
    const u32* wr = &Wt[e2*132 + tc*8];
    #pragma unroll
    for(int cj=0; cj<8; ++cj){
      f16x2 wv = __builtin_bit_cast(f16x2, wr[cj]);
      acc0[cj] = fdot2a(a0, wv, acc0[cj]);
      acc1[cj] = fdot2a(a1, wv, acc1[cj]);
    }
  }

  float4 b0 = *(const float4*)(bias + tc*8);
  float4 b1 = *(const float4*)(bias + tc*8 + 4);
  float* o0 = io + (row0 + tr)*NE + tc*8;
  float* o1 = io + (row0 + tr + 16)*NE + tc*8;
  float4 v;
  v.x = acc0[0]+b0.x; v.y = acc0[1]+b0.y; v.z = acc0[2]+b0.z; v.w = acc0[3]+b0.w;
  *(float4*)(o0) = v;
  v.x = acc0[4]+b1.x; v.y = acc0[5]+b1.y; v.z = acc0[6]+b1.z; v.w = acc0[7]+b1.w;
  *(float4*)(o0+4) = v;
  v.x = acc1[0]+b0.x; v.y = acc1[1]+b0.y; v.z = acc1[2]+b0.z; v.w = acc1[3]+b0.w;
  *(float4*)(o1) = v;
  v.x = acc1[4]+b1.x; v.y = acc1[5]+b1.y; v.z = acc1[6]+b1.z; v.w = acc1[7]+b1.w;
  *(float4*)(o1+4) = v;
}

extern "C" void kernel_launch(void* const* d_in, const int* in_sizes, int n_in,
                              void* d_out, int out_size, void* d_ws, size_t ws_size,
                              hipStream_t stream) {
  (void)in_sizes; (void)n_in; (void)out_size; (void)d_ws; (void)ws_size;
  const float* x     = (const float*)d_in[0];
  const float* theta = (const float*)d_in[1];
  const float* W     = (const float*)d_in[2];
  const float* bias  = (const float*)d_in[3];
  float* out = (float*)d_out;

  // attention writes attn_out[b][s][h][d] into d_out (scratch), combine is
  // in-place (each block stages its own rows to LDS before overwriting).
  qattn<<<512, 256, 0, stream>>>(x, theta, out);
  qcomb<<<256, 256, 0, stream>>>(W, bias, out);
}

// Round 3
// 48.953 us; speedup vs baseline: 1.1653x; 1.1653x over previous
//
#include <hip/hip_runtime.h>

typedef _Float16 f16;
typedef _Float16 f16x2 __attribute__((ext_vector_type(2)));
typedef _Float16 f16x4 __attribute__((ext_vector_type(4)));
typedef float    f32x4 __attribute__((ext_vector_type(4)));
typedef unsigned int u32;
typedef unsigned int u32x2v __attribute__((ext_vector_type(2)));

#define NB 4
#define NS 2048
#define NH 16
#define NDK 8
#define NE 128
// log2(e)/sqrt(8): exp(dot/sqrt(8)) == exp2(dot * CSCALE)
#define CSCALE 0.51006972f

__device__ __forceinline__ float fexp2(float v){
#if __has_builtin(__builtin_amdgcn_exp2f)
  return __builtin_amdgcn_exp2f(v);
#else
  return exp2f(v);
#endif
}

__device__ __forceinline__ f16x2 pkrtz(float a, float b){
  return __builtin_bit_cast(f16x2, __builtin_amdgcn_cvt_pkrtz(a, b));
}

__device__ __forceinline__ float fdot2a(f16x2 a, f16x2 b, float c){
#if __has_builtin(__builtin_amdgcn_fdot2)
  return __builtin_amdgcn_fdot2(a, b, c, false);
#else
  return c + (float)a[0]*(float)b[0] + (float)a[1]*(float)b[1];
#endif
}

// ---------------------------------------------------------------------------
// Attention kernel: one block = one (b,h) pair x 256 query rows, 512 threads
// (8 waves x 32 q-rows) so 2 blocks/CU = 4 waves/SIMD (latency hiding; was 2).
// q=k=v = cos(x+theta) computed in-staging (f16).
// LDS: Kl = rows [2048][8] f16 (32KB), Vl = V^T [8][2048] f16 XOR-swizzled (32KB).
// Per kt tile of 16 keys:
//   S^T = mfma16x16x16f16(A=K-rows, B=Q-rows*CSCALE)  (dk=8 zero-padded via B)
//   P = exp2(S^T) -> cvt_pkrtz -> directly the B operand of
//   out^T += mfma16x16x16f16(A=V^T (rows>=8 == 1.0), B=P^T)
// Accumulator row 8 = softmax denominator (ones trick).
// ---------------------------------------------------------------------------
__global__ __launch_bounds__(512, 4) void qattn(const float* __restrict__ x,
                                                const float* __restrict__ theta,
                                                float* __restrict__ out){
  __shared__ __align__(16) uint2 Kl[NS*2];   // [s][2] : 16B per row
  __shared__ __align__(16) uint2 Vl[8*512];  // [d][512 8B-granules, swizzled]

  const int bid = blockIdx.x;
  const int bh  = bid >> 3;       // 0..63
  const int qc  = bid & 7;        // q-chunk of 256 rows
  const int b   = bh >> 4;
  const int h   = bh & 15;
  const int tid = threadIdx.x;

  const float4 th0 = *(const float4*)(theta);
  const float4 th1 = *(const float4*)(theta + 4);

  // ---- stage: compute cos(x+theta) for all 2048 rows of this (b,h) ----
  const float* xb = x + ((size_t)b*NS*NH + h)*NDK;
  unsigned short* Vs = (unsigned short*)Vl;
  #pragma unroll
  for(int i=0;i<4;++i){
    int s = tid + 512*i;
    const float4* xp = (const float4*)(xb + (size_t)s*(NH*NDK));
    float4 x0 = xp[0], x1 = xp[1];
    union { f16 hh[8]; uint4 u; } pk;
    pk.hh[0] = (f16)__cosf(x0.x + th0.x);
    pk.hh[1] = (f16)__cosf(x0.y + th0.y);
    pk.hh[2] = (f16)__cosf(x0.z + th0.z);
    pk.hh[3] = (f16)__cosf(x0.w + th0.w);
    pk.hh[4] = (f16)__cosf(x1.x + th1.x);
    pk.hh[5] = (f16)__cosf(x1.y + th1.y);
    pk.hh[6] = (f16)__cosf(x1.z + th1.z);
    pk.hh[7] = (f16)__cosf(x1.w + th1.w);
    ((uint4*)Kl)[s] = pk.u;
    int sb = s >> 2, sl = s & 3;
    #pragma unroll
    for(int d=0;d<8;++d)
      Vs[(d<<11) + (((sb ^ d)<<2) | sl)] =
          __builtin_bit_cast(unsigned short, pk.hh[d]);
  }
  __syncthreads();

  const int lane = tid & 63;
  const int w    = tid >> 6;      // 0..7
  const int c    = lane & 15;     // column role (q for QK-B / d for V-A)
  const int grp  = lane >> 4;     // 0..3
  const int g1   = grp & 1;
  const bool lo32  = (lane < 32);
  const bool creal = (c < 8);
  const int dvx  = c & 7;
  const int qbase = qc*256 + w*32;

  // hoisted Q fragments (B operand of swapped QK), pre-scaled by CSCALE so the
  // MFMA output is already the exp2 argument; zero lanes>=32 pads dk 8->16
  f16x4 qf[2];
  #pragma unroll
  for(int sub=0; sub<2; ++sub){
    uint2 qv = Kl[(qbase + sub*16 + c)*2 + g1];
    if(!lo32){ qv.x = 0u; qv.y = 0u; }
    f16x4 q4 = __builtin_bit_cast(f16x4, qv);
    const f16 cs = (f16)CSCALE;
    q4[0] = q4[0]*cs; q4[1] = q4[1]*cs; q4[2] = q4[2]*cs; q4[3] = q4[3]*cs;
    qf[sub] = q4;
  }

  const f32x4 z4 = {0.f,0.f,0.f,0.f};
  f32x4 acc[2] = {z4,z4};
  uint2 ones2; ones2.x = 0x3C003C00u; ones2.y = 0x3C003C00u;  // f16 1.0 x4

  const uint2* kptr = &Kl[c*2 + g1];
  for(int kt=0; kt<128; ++kt){
    uint2 ka = kptr[kt*32];                                 // K row kt*16+c
    uint2 va = Vl[(dvx<<9) | (((kt<<2) + grp) ^ dvx)];      // V^T row c
    if(!creal) va = ones2;                                  // rows 8..15 = 1.0
    f16x4 kf = __builtin_bit_cast(f16x4, ka);
    f16x4 vf = __builtin_bit_cast(f16x4, va);
    #pragma unroll
    for(int sub=0; sub<2; ++sub){
      f32x4 st = __builtin_amdgcn_mfma_f32_16x16x16f16(kf, qf[sub], z4, 0, 0, 0);
      float p0 = fexp2(st[0]);
      float p1 = fexp2(st[1]);
      float p2 = fexp2(st[2]);
      float p3 = fexp2(st[3]);
      f16x2 plo = pkrtz(p0, p1);
      f16x2 phi = pkrtz(p2, p3);
      u32x2v pu = { __builtin_bit_cast(u32, plo), __builtin_bit_cast(u32, phi) };
      f16x4 pf = __builtin_bit_cast(f16x4, pu);
      acc[sub] = __builtin_amdgcn_mfma_f32_16x16x16f16(vf, pf, acc[sub], 0, 0, 0);
    }
  }

  // epilogue: acc row 8 (lane 32+c, reg0) = denominator for column q=c
  #pragma unroll
  for(int sub=0; sub<2; ++sub){
    float den = __shfl(acc[sub][0], 32 + c, 64);
    if(lo32){
      float inv = 1.0f / den;
      int q = qbase + sub*16 + c;
      float4 o;
      o.x = acc[sub][0]*inv;
      o.y = acc[sub][1]*inv;
      o.z = acc[sub][2]*inv;
      o.w = acc[sub][3]*inv;
      // attn_out[b][q][h][d], d = 4*grp + r  (written into d_out as scratch)
      *(float4*)(out + ((size_t)(b*NS + q)*NH + h)*NDK + grp*4) = o;
    }
  }
}

// ---------------------------------------------------------------------------
// Combine: out = attn @ W^T + bias, in-place on d_out.
// Block = 32 rows. A rows staged to LDS (f16 pairs) BEFORE overwrite -> safe
// in-place. W transposed to half2 pairs in LDS (padded stride 132 for
// conflict-free b128 reads). Inner loop uses v_dot2_f32_f16.
// ---------------------------------------------------------------------------
__global__ __launch_bounds__(256) void qcomb(const float* __restrict__ W,
                                             const float* __restrict__ bias,
                                             float* __restrict__ io){
  __shared__ __align__(16) u32 Wt[64*132];   // Wt[e2*132 + j] = {W[j][2e2],W[j][2e2+1]}
  __shared__ __align__(16) u32 A2[32*65];    // A2[r*65 + e2]  = {A[r][2e2],A[r][2e2+1]}
  const int tid = threadIdx.x;
  const size_t row0 = (size_t)blockIdx.x * 32;

  #pragma unroll
  for(int i=0;i<32;++i){
    int g = tid + 256*i;          // 0..8191
    int j = g >> 6, e2 = g & 63;
    const float* wp = W + (size_t)j*NE + 2*e2;
    f16x2 wv = pkrtz(wp[0], wp[1]);
    Wt[e2*132 + j] = __builtin_bit_cast(u32, wv);
  }
  #pragma unroll
  for(int i=0;i<8;++i){
    int g = tid + 256*i;          // 0..2047
    int r = g >> 6, e2 = g & 63;
    const float* ap = io + (row0 + r)*NE + 2*e2;
    f16x2 av = pkrtz(ap[0], ap[1]);
    A2[r*65 + e2] = __builtin_bit_cast(u32, av);
  }
  __syncthreads();

  const int tr = tid >> 4, tc = tid & 15;
  float acc0[8] = {0,0,0,0,0,0,0,0};
  float acc1[8] = {0,0,0,0,0,0,0,0};
  for(int e2=0; e2<64; ++e2){
    f16x2 a0 = __builtin_bit_cast(f16x2, A2[tr*65 + e2]);
    f16x2 a1 = __builtin_bit_cast(f16x2, A2[(tr+16)*65 + e2]);
    const u32* wr = &Wt[e2*132 + tc*8];
    #pragma unroll
    for(int cj=0; cj<8; ++cj){
      f16x2 wv = __builtin_bit_cast(f16x2, wr[cj]);
      acc0[cj] = fdot2a(a0, wv, acc0[cj]);
      acc1[cj] = fdot2a(a1, wv, acc1[cj]);
    }
  }

  float4 b0 = *(const float4*)(bias + tc*8);
  float4 b1 = *(const float4*)(bias + tc*8 + 4);
  float* o0 = io + (row0 + tr)*NE + tc*8;
  float* o1 = io + (row0 + tr + 16)*NE + tc*8;
  float4 v;
  v.x = acc0[0]+b0.x; v.y = acc0[1]+b0.y; v.z = acc0[2]+b0.z; v.w = acc0[3]+b0.w;
  *(float4*)(o0) = v;
  v.x = acc0[4]+b1.x; v.y = acc0[5]+b1.y; v.z = acc0[6]+b1.z; v.w = acc0[7]+b1.w;
  *(float4*)(o0+4) = v;
  v.x = acc1[0]+b0.x; v.y = acc1[1]+b0.y; v.z = acc1[2]+b0.z; v.w = acc1[3]+b0.w;
  *(float4*)(o1) = v;
  v.x = acc1[4]+b1.x; v.y = acc1[5]+b1.y; v.z = acc1[6]+b1.z; v.w = acc1[7]+b1.w;
  *(float4*)(o1+4) = v;
}

extern "C" void kernel_launch(void* const* d_in, const int* in_sizes, int n_in,
                              void* d_out, int out_size, void* d_ws, size_t ws_size,
                              hipStream_t stream) {
  (void)in_sizes; (void)n_in; (void)out_size; (void)d_ws; (void)ws_size;
  const float* x     = (const float*)d_in[0];
  const float* theta = (const float*)d_in[1];
  const float* W     = (const float*)d_in[2];
  const float* bias  = (const float*)d_in[3];
  float* out = (float*)d_out;

  // attention writes attn_out[b][s][h][d] into d_out (scratch), combine is
  // in-place (each block stages its own rows to LDS before overwriting).
  qattn<<<512, 512, 0, stream>>>(x, theta, out);
  qcomb<<<256, 256, 0, stream>>>(W, bias, out);
}